// Round 1
// baseline (236.288 us; speedup 1.0000x reference)
//
#include <hip/hip_runtime.h>

// DeepSets fused kernel for MI355X (gfx950).
// phi = relu(relu(x@pw1+pb1)@pw2+pb2)  ; pooled fp = (sum_n h2_n)@pw3 + N*pb3
// Strategy: bf16 MFMA (16x16x32) with WEIGHT hi/lo split (2 MFMAs/matmul) to kill
// systematic quantization error; x/h1 plain bf16 (random error cancels over N).
// ws usage: gsum(1KB) + w1hi/lo(64KB) + w2hi/lo(256KB) ~= 321KB.

typedef unsigned short u16;
typedef short bf16x8 __attribute__((ext_vector_type(8)));
typedef float f32x4 __attribute__((ext_vector_type(4)));

__device__ __forceinline__ u16 f2bf(float f) {
    unsigned u = __float_as_uint(f);
    return (u16)((u + 0x7FFFu + ((u >> 16) & 1u)) >> 16);
}
__device__ __forceinline__ float bf2f(u16 h) {
    return __uint_as_float(((unsigned)h) << 16);
}

// ---------------- prep: quantize weights into fragment order, zero gsum ------
// B-fragment layout for mfma_f32_16x16x32_bf16: lane l holds B[k=32*ks+8*(l>>4)+j][col=16*ct+(l&15)]
// stored as frag[((ct*KS+ks)*64 + l)*8 + j]  -> each wave load is 1KB contiguous.
__global__ void prep_kernel(const float* __restrict__ pw1, const float* __restrict__ pw2,
                            u16* __restrict__ w1hi, u16* __restrict__ w1lo,
                            u16* __restrict__ w2hi, u16* __restrict__ w2lo,
                            float* __restrict__ gsum) {
    int idx = blockIdx.x * blockDim.x + threadIdx.x;   // 160*512 = 81920
    if (idx < 256) gsum[idx] = 0.f;
    if (idx < 16384) {  // pw1: 64x256, KS=2
        int j = idx & 7, l = (idx >> 3) & 63, ks = (idx >> 9) & 1, ct = idx >> 10;
        int k = 32 * ks + 8 * (l >> 4) + j;
        int col = 16 * ct + (l & 15);
        float v = pw1[k * 256 + col];
        u16 hi = f2bf(v);
        w1hi[idx] = hi;
        w1lo[idx] = f2bf(v - bf2f(hi));
    } else {            // pw2: 256x256, KS=8
        int o = idx - 16384;
        int j = o & 7, l = (o >> 3) & 63, ks = (o >> 9) & 7, ct = o >> 12;
        int k = 32 * ks + 8 * (l >> 4) + j;
        int col = 16 * ct + (l & 15);
        float v = pw2[k * 256 + col];
        u16 hi = f2bf(v);
        w2hi[o] = hi;
        w2lo[o] = f2bf(v - bf2f(hi));
    }
}

// ---------------- fused phi + pool ------------------------------------------
// One block = one 64-row tile. 512 threads = 8 waves; wave w owns cols [32w,32w+32).
__global__ __launch_bounds__(512) void phi_kernel(
    const float* __restrict__ x,
    const float* __restrict__ pb1, const float* __restrict__ pb2,
    const u16* __restrict__ w1hi, const u16* __restrict__ w1lo,
    const u16* __restrict__ w2hi, const u16* __restrict__ w2lo,
    float* __restrict__ gsum, int ntiles) {
    __shared__ __align__(16) u16 xs[64 * 64];      // bf16 x tile, swizzled (^ (row&7)<<4)
    __shared__ __align__(16) u16 h1s[64 * 256];    // bf16 h1 tile, swizzled (^ (row&15)<<4)
    __shared__ float colsum[256];

    const int tile = blockIdx.x;
    if (tile >= ntiles) return;
    const int tid = threadIdx.x;
    const int l = tid & 63;
    const int w = tid >> 6;
    const int fr = l & 15;     // A row / B col / C col within 16-tile
    const int fg = l >> 4;     // k-chunk group (A/B), row group (C)

    if (tid < 256) colsum[tid] = 0.f;

    // ---- stage x tile: 64 rows x 64 cols fp32 -> bf16 LDS (swizzled)
    const float4* xg = (const float4*)(x + (size_t)tile * 4096);
#pragma unroll
    for (int i = 0; i < 2; ++i) {
        int f4 = tid + i * 512;           // 0..1023
        int row = f4 >> 4, c4 = f4 & 15;  // 16 float4 per row
        float4 v = xg[f4];
        ushort4 b;
        b.x = f2bf(v.x); b.y = f2bf(v.y); b.z = f2bf(v.z); b.w = f2bf(v.w);
        int byte = (row * 128 + c4 * 8) ^ ((row & 7) << 4);
        *(ushort4*)((char*)xs + byte) = b;
    }
    __syncthreads();

    // ---- GEMM1: h1 = relu(x @ pw1 + pb1), K=64 (2 k-steps)
    {
        f32x4 acc[2][4] = {};
#pragma unroll
        for (int ks = 0; ks < 2; ++ks) {
            bf16x8 a[4];
#pragma unroll
            for (int rt = 0; rt < 4; ++rt) {
                int row = (rt << 4) + fr;
                int byte = ((row << 7) + (ks << 6) + (fg << 4)) ^ ((row & 7) << 4);
                a[rt] = *(const bf16x8*)((char*)xs + byte);
            }
#pragma unroll
            for (int ct = 0; ct < 2; ++ct) {
                int ctg = 2 * w + ct;
                bf16x8 bh = *(const bf16x8*)(w1hi + (((ctg << 1) + ks) << 9) + (l << 3));
                bf16x8 bl = *(const bf16x8*)(w1lo + (((ctg << 1) + ks) << 9) + (l << 3));
#pragma unroll
                for (int rt = 0; rt < 4; ++rt) {
                    acc[ct][rt] = __builtin_amdgcn_mfma_f32_16x16x32_bf16(a[rt], bh, acc[ct][rt], 0, 0, 0);
                    acc[ct][rt] = __builtin_amdgcn_mfma_f32_16x16x32_bf16(a[rt], bl, acc[ct][rt], 0, 0, 0);
                }
            }
        }
        // epilogue: bias + relu -> h1s (bf16, swizzled)
#pragma unroll
        for (int ct = 0; ct < 2; ++ct) {
            int ctg = 2 * w + ct;
            int col = (ctg << 4) + fr;
            float bias = pb1[col];
#pragma unroll
            for (int rt = 0; rt < 4; ++rt)
#pragma unroll
                for (int r = 0; r < 4; ++r) {
                    int row = (rt << 4) + (fg << 2) + r;
                    float hv = fmaxf(acc[ct][rt][r] + bias, 0.f);
                    int byte = ((row << 9) + (col << 1)) ^ ((row & 15) << 4);
                    *(u16*)((char*)h1s + byte) = f2bf(hv);
                }
        }
    }
    __syncthreads();

    // ---- GEMM2: h2 = relu(h1 @ pw2 + pb2), K=256 (8 k-steps); column-sum pool
    {
        f32x4 acc[2][4] = {};
#pragma unroll
        for (int ks = 0; ks < 8; ++ks) {
            bf16x8 a[4];
#pragma unroll
            for (int rt = 0; rt < 4; ++rt) {
                int row = (rt << 4) + fr;
                int byte = ((row << 9) + (ks << 6) + (fg << 4)) ^ ((row & 15) << 4);
                a[rt] = *(const bf16x8*)((char*)h1s + byte);
            }
#pragma unroll
            for (int ct = 0; ct < 2; ++ct) {
                int ctg = 2 * w + ct;
                bf16x8 bh = *(const bf16x8*)(w2hi + (((ctg << 3) + ks) << 9) + (l << 3));
                bf16x8 bl = *(const bf16x8*)(w2lo + (((ctg << 3) + ks) << 9) + (l << 3));
#pragma unroll
                for (int rt = 0; rt < 4; ++rt) {
                    acc[ct][rt] = __builtin_amdgcn_mfma_f32_16x16x32_bf16(a[rt], bh, acc[ct][rt], 0, 0, 0);
                    acc[ct][rt] = __builtin_amdgcn_mfma_f32_16x16x32_bf16(a[rt], bl, acc[ct][rt], 0, 0, 0);
                }
            }
        }
#pragma unroll
        for (int ct = 0; ct < 2; ++ct) {
            int ctg = 2 * w + ct;
            int col = (ctg << 4) + fr;
            float bias = pb2[col];
            float part = 0.f;
#pragma unroll
            for (int rt = 0; rt < 4; ++rt)
#pragma unroll
                for (int r = 0; r < 4; ++r)
                    part += fmaxf(acc[ct][rt][r] + bias, 0.f);
            atomicAdd(&colsum[col], part);
        }
    }
    __syncthreads();
    if (tid < 256) atomicAdd(&gsum[tid], colsum[tid]);
}

// ---------------- tail: pw3-pool collapse + rho + head (fp32, one block) ----
__global__ void tail_kernel(const float* __restrict__ gsum, const float* __restrict__ xst,
                            const float* __restrict__ pw3, const float* __restrict__ pb3,
                            const float* __restrict__ rw1, const float* __restrict__ rb1,
                            const float* __restrict__ rw2, const float* __restrict__ rb2,
                            const float* __restrict__ rw3, const float* __restrict__ rb3,
                            const float* __restrict__ w1, const float* __restrict__ b1,
                            const float* __restrict__ w2, const float* __restrict__ b2,
                            const float* __restrict__ w3, const float* __restrict__ b3,
                            float* __restrict__ out, float nf) {
    __shared__ float fp[128], r1[256], r2[256], tc[144], t1[256], t2[256];
    int t = threadIdx.x;
    if (t < 128) {
        float s = nf * pb3[t];
        for (int j = 0; j < 256; ++j) s += gsum[j] * pw3[j * 128 + t];
        fp[t] = s;
    }
    __syncthreads();
    { float s = rb1[t]; for (int f = 0; f < 128; ++f) s += fp[f] * rw1[f * 256 + t]; r1[t] = fmaxf(s, 0.f); }
    __syncthreads();
    { float s = rb2[t]; for (int h = 0; h < 256; ++h) s += r1[h] * rw2[h * 256 + t]; r2[t] = fmaxf(s, 0.f); }
    __syncthreads();
    if (t < 128) {
        float s = rb3[t];
        for (int h = 0; h < 256; ++h) s += r2[h] * rw3[h * 128 + t];
        tc[t] = s;
    } else if (t < 144) {
        tc[t] = xst[t - 128];
    }
    __syncthreads();
    { float s = b1[t]; for (int i = 0; i < 144; ++i) s += tc[i] * w1[i * 256 + t]; t1[t] = fmaxf(s, 0.f); }
    __syncthreads();
    { float s = b2[t]; for (int h = 0; h < 256; ++h) s += t1[h] * w2[h * 256 + t]; t2[t] = fmaxf(s, 0.f); }
    __syncthreads();
    if (t < 5) {
        float s = b3[t];
        for (int h = 0; h < 256; ++h) s += t2[h] * w3[h * 5 + t];
        out[t] = s;
    }
}

extern "C" void kernel_launch(void* const* d_in, const int* in_sizes, int n_in,
                              void* d_out, int out_size, void* d_ws, size_t ws_size,
                              hipStream_t stream) {
    (void)n_in; (void)out_size; (void)ws_size;
    const float* x   = (const float*)d_in[0];
    const float* xst = (const float*)d_in[1];
    const float* pw1 = (const float*)d_in[2];
    const float* pb1 = (const float*)d_in[3];
    const float* pw2 = (const float*)d_in[4];
    const float* pb2 = (const float*)d_in[5];
    const float* pw3 = (const float*)d_in[6];
    const float* pb3 = (const float*)d_in[7];
    const float* rw1 = (const float*)d_in[8];
    const float* rb1 = (const float*)d_in[9];
    const float* rw2 = (const float*)d_in[10];
    const float* rb2 = (const float*)d_in[11];
    const float* rw3 = (const float*)d_in[12];
    const float* rb3 = (const float*)d_in[13];
    const float* w1  = (const float*)d_in[14];
    const float* b1  = (const float*)d_in[15];
    const float* w2  = (const float*)d_in[16];
    const float* b2  = (const float*)d_in[17];
    const float* w3  = (const float*)d_in[18];
    const float* b3  = (const float*)d_in[19];
    float* out = (float*)d_out;

    int n = in_sizes[0] / 64;      // 400000
    int ntiles = n >> 6;           // 6250 (exact)

    char* ws = (char*)d_ws;
    float* gsum = (float*)ws;                    // 256 f32
    u16* w1hi = (u16*)(ws + 1024);               // 16384 bf16
    u16* w1lo = (u16*)(ws + 33792);              // 16384 bf16
    u16* w2hi = (u16*)(ws + 66560);              // 65536 bf16
    u16* w2lo = (u16*)(ws + 197632);             // 65536 bf16

    prep_kernel<<<160, 512, 0, stream>>>(pw1, pw2, w1hi, w1lo, w2hi, w2lo, gsum);
    phi_kernel<<<ntiles, 512, 0, stream>>>(x, pb1, pb2, w1hi, w1lo, w2hi, w2lo, gsum, ntiles);
    tail_kernel<<<1, 256, 0, stream>>>(gsum, xst, pw3, pb3, rw1, rb1, rw2, rb2,
                                       rw3, rb3, w1, b1, w2, b2, w3, b3, out, (float)n);
}

// Round 2
// 214.967 us; speedup vs baseline: 1.0992x; 1.0992x over previous
//
#include <hip/hip_runtime.h>

// DeepSets fused kernel for MI355X (gfx950) — round 2.
// Persistent blocks (256 = 1/CU), ALL weight fragments held in VGPRs
// (A-operand of MFMA = weights, B-operand = data; D comes out transposed:
// lane holds 4 consecutive h-cols of one row -> b64 LDS writes).
// One barrier per tile iteration; x double-buffered via register prefetch.

typedef unsigned short u16;
typedef short bf16x8 __attribute__((ext_vector_type(8)));
typedef float f32x4 __attribute__((ext_vector_type(4)));

#define NBLK 256

__device__ __forceinline__ u16 f2bf(float f) {
    unsigned u = __float_as_uint(f);
    return (u16)((u + 0x7FFFu + ((u >> 16) & 1u)) >> 16);
}
__device__ __forceinline__ float bf2f(u16 h) {
    return __uint_as_float(((unsigned)h) << 16);
}

// ---------------- prep: quantize weights into fragment order, zero gsum ------
// Fragment layout (validated r0): lane l, elem j holds W[k=32*ks+8*(l>>4)+j][16*ctg+(l&15)]
// at frag[((ctg*KS+ks)*64 + l)*8 + j]. Used as the MFMA *A* operand now
// (A[i=l&15][k=8*(l>>4)+j] = W[k][16ctg+i]), computing D = W^T X^T = (XW)^T.
__global__ void prep_kernel(const float* __restrict__ pw1, const float* __restrict__ pw2,
                            u16* __restrict__ w1hi, u16* __restrict__ w1lo,
                            u16* __restrict__ w2hi, u16* __restrict__ w2lo,
                            float* __restrict__ gsum) {
    int idx = blockIdx.x * blockDim.x + threadIdx.x;   // 160*512 = 81920
    if (idx < 256) gsum[idx] = 0.f;
    if (idx < 16384) {  // pw1: 64x256, KS=2
        int j = idx & 7, l = (idx >> 3) & 63, ks = (idx >> 9) & 1, ct = idx >> 10;
        int k = 32 * ks + 8 * (l >> 4) + j;
        int col = 16 * ct + (l & 15);
        float v = pw1[k * 256 + col];
        u16 hi = f2bf(v);
        w1hi[idx] = hi;
        w1lo[idx] = f2bf(v - bf2f(hi));
    } else {            // pw2: 256x256, KS=8
        int o = idx - 16384;
        int j = o & 7, l = (o >> 3) & 63, ks = (o >> 9) & 7, ct = o >> 12;
        int k = 32 * ks + 8 * (l >> 4) + j;
        int col = 16 * ct + (l & 15);
        float v = pw2[k * 256 + col];
        u16 hi = f2bf(v);
        w2hi[o] = hi;
        w2lo[o] = f2bf(v - bf2f(hi));
    }
}

// ---------------- fused phi + pool (persistent) ------------------------------
__global__ __launch_bounds__(512, 2) void phi_kernel(
    const float* __restrict__ x,
    const float* __restrict__ pb1, const float* __restrict__ pb2,
    const u16* __restrict__ w1hi, const u16* __restrict__ w1lo,
    const u16* __restrict__ w2hi, const u16* __restrict__ w2lo,
    float* __restrict__ gsum, int ntiles) {
    __shared__ __align__(16) u16 xs[2][64 * 64];    // x tile bf16, swz ^((row&7)<<4)
    __shared__ __align__(16) u16 h1s[2][64 * 256];  // h1 tile bf16, swz ^((row&15)<<4)

    const int tid = threadIdx.x;
    const int l = tid & 63;
    const int w = tid >> 6;
    const int fr = l & 15;
    const int fg = l >> 4;
    const int wb = w * 32;

    // ---- preload weight fragments into registers (loop-invariant)
    bf16x8 w1h[2][2], w1l[2][2];   // [ct][ks]
#pragma unroll
    for (int ct = 0; ct < 2; ++ct)
#pragma unroll
        for (int ks = 0; ks < 2; ++ks) {
            int ctg = 2 * w + ct;
            int off = (((ctg << 1) + ks) << 9) + (l << 3);
            w1h[ct][ks] = *(const bf16x8*)(w1hi + off);
            w1l[ct][ks] = *(const bf16x8*)(w1lo + off);
        }
    bf16x8 w2h[2][8], w2l[2][8];   // [ct][ks]
#pragma unroll
    for (int ct = 0; ct < 2; ++ct)
#pragma unroll
        for (int ks = 0; ks < 8; ++ks) {
            int ctg = 2 * w + ct;
            int off = (((ctg << 3) + ks) << 9) + (l << 3);
            w2h[ct][ks] = *(const bf16x8*)(w2hi + off);
            w2l[ct][ks] = *(const bf16x8*)(w2lo + off);
        }
    f32x4 b1v[2], b2v[2];
#pragma unroll
    for (int ct = 0; ct < 2; ++ct) {
        int c0 = wb + ct * 16 + fg * 4;
        b1v[ct] = *(const f32x4*)(pb1 + c0);
        b2v[ct] = *(const f32x4*)(pb2 + c0);
    }

    float psum[2][4] = {{0.f, 0.f, 0.f, 0.f}, {0.f, 0.f, 0.f, 0.f}};

    const int t0 = blockIdx.x;
    // ---- prologue: stage tile t0 into xs[0], prefetch t0+NBLK into regs
    {
        const float4* xg = (const float4*)(x + (size_t)t0 * 4096);
#pragma unroll
        for (int i = 0; i < 2; ++i) {
            int f4 = tid + i * 512;
            float4 v = xg[f4];
            int row = f4 >> 4, c4 = f4 & 15;
            ushort4 b;
            b.x = f2bf(v.x); b.y = f2bf(v.y); b.z = f2bf(v.z); b.w = f2bf(v.w);
            int byte = (row * 128 + c4 * 8) ^ ((row & 7) << 4);
            *(ushort4*)((char*)xs[0] + byte) = b;
        }
    }
    float4 pf0, pf1;
    {
        int tn = (t0 + NBLK < ntiles) ? t0 + NBLK : 0;
        const float4* xg = (const float4*)(x + (size_t)tn * 4096);
        pf0 = xg[tid];
        pf1 = xg[tid + 512];
    }
    __syncthreads();

    int buf = 0, hb = 0;
    for (int t = t0; t < ntiles; t += NBLK) {
        // ---- GEMM1: D1 = (x@pw1)^T over this tile, from xs[buf]
        {
            f32x4 acc[2][4] = {};
#pragma unroll
            for (int ks = 0; ks < 2; ++ks) {
                bf16x8 bd[4];
#pragma unroll
                for (int rt = 0; rt < 4; ++rt) {
                    int row = (rt << 4) + fr;
                    int byte = ((row << 7) + (ks << 6) + (fg << 4)) ^ ((row & 7) << 4);
                    bd[rt] = *(const bf16x8*)((char*)xs[buf] + byte);
                }
#pragma unroll
                for (int ct = 0; ct < 2; ++ct)
#pragma unroll
                    for (int rt = 0; rt < 4; ++rt) {
                        acc[ct][rt] = __builtin_amdgcn_mfma_f32_16x16x32_bf16(w1h[ct][ks], bd[rt], acc[ct][rt], 0, 0, 0);
                        acc[ct][rt] = __builtin_amdgcn_mfma_f32_16x16x32_bf16(w1l[ct][ks], bd[rt], acc[ct][rt], 0, 0, 0);
                    }
            }
            // epilogue: bias+relu, lane holds hcols c0..c0+3 of row rown -> b64 write
#pragma unroll
            for (int ct = 0; ct < 2; ++ct) {
                int c0 = wb + ct * 16 + fg * 4;
#pragma unroll
                for (int rt = 0; rt < 4; ++rt) {
                    int rown = (rt << 4) + fr;
                    ushort4 o;
                    o.x = f2bf(fmaxf(acc[ct][rt][0] + b1v[ct][0], 0.f));
                    o.y = f2bf(fmaxf(acc[ct][rt][1] + b1v[ct][1], 0.f));
                    o.z = f2bf(fmaxf(acc[ct][rt][2] + b1v[ct][2], 0.f));
                    o.w = f2bf(fmaxf(acc[ct][rt][3] + b1v[ct][3], 0.f));
                    int byte = ((rown << 9) + (c0 << 1)) ^ ((rown & 15) << 4);
                    *(ushort4*)((char*)h1s[hb] + byte) = o;
                }
            }
        }
        // ---- stage next x tile (regs -> xs[buf^1]); prefetch t+2*NBLK
#pragma unroll
        for (int i = 0; i < 2; ++i) {
            float4 v = i ? pf1 : pf0;
            int f4 = tid + i * 512;
            int row = f4 >> 4, c4 = f4 & 15;
            ushort4 b;
            b.x = f2bf(v.x); b.y = f2bf(v.y); b.z = f2bf(v.z); b.w = f2bf(v.w);
            int byte = (row * 128 + c4 * 8) ^ ((row & 7) << 4);
            *(ushort4*)((char*)xs[buf ^ 1] + byte) = b;
        }
        {
            int tn = (t + 2 * NBLK < ntiles) ? t + 2 * NBLK : 0;
            const float4* xg = (const float4*)(x + (size_t)tn * 4096);
            pf0 = xg[tid];
            pf1 = xg[tid + 512];
        }
        __syncthreads();   // h1s[hb] + xs[buf^1] now visible

        // ---- GEMM2: D2 = (h1@pw2)^T, pool into psum
        {
            f32x4 acc2[2][4] = {};
#pragma unroll
            for (int ks = 0; ks < 8; ++ks) {
                bf16x8 bd[4];
#pragma unroll
                for (int rt = 0; rt < 4; ++rt) {
                    int row = (rt << 4) + fr;
                    int byte = ((row << 9) + (ks << 6) + (fg << 4)) ^ ((row & 15) << 4);
                    bd[rt] = *(const bf16x8*)((char*)h1s[hb] + byte);
                }
#pragma unroll
                for (int ct = 0; ct < 2; ++ct)
#pragma unroll
                    for (int rt = 0; rt < 4; ++rt) {
                        acc2[ct][rt] = __builtin_amdgcn_mfma_f32_16x16x32_bf16(w2h[ct][ks], bd[rt], acc2[ct][rt], 0, 0, 0);
                        acc2[ct][rt] = __builtin_amdgcn_mfma_f32_16x16x32_bf16(w2l[ct][ks], bd[rt], acc2[ct][rt], 0, 0, 0);
                    }
            }
#pragma unroll
            for (int ct = 0; ct < 2; ++ct)
#pragma unroll
                for (int r = 0; r < 4; ++r) {
                    float v = 0.f;
#pragma unroll
                    for (int rt = 0; rt < 4; ++rt)
                        v += fmaxf(acc2[ct][rt][r] + b2v[ct][r], 0.f);
                    psum[ct][r] += v;
                }
        }
        buf ^= 1;
        hb ^= 1;
    }

    // ---- final: reduce psum over the 16 fr-lanes, one atomicAdd per col
#pragma unroll
    for (int ct = 0; ct < 2; ++ct)
#pragma unroll
        for (int r = 0; r < 4; ++r) {
            float v = psum[ct][r];
            v += __shfl_xor(v, 1, 64);
            v += __shfl_xor(v, 2, 64);
            v += __shfl_xor(v, 4, 64);
            v += __shfl_xor(v, 8, 64);
            if (fr == 0) atomicAdd(&gsum[wb + ct * 16 + fg * 4 + r], v);
        }
}

// ---------------- tail: pw3-pool collapse + rho + head (fp32, one block) ----
__global__ void tail_kernel(const float* __restrict__ gsum, const float* __restrict__ xst,
                            const float* __restrict__ pw3, const float* __restrict__ pb3,
                            const float* __restrict__ rw1, const float* __restrict__ rb1,
                            const float* __restrict__ rw2, const float* __restrict__ rb2,
                            const float* __restrict__ rw3, const float* __restrict__ rb3,
                            const float* __restrict__ w1, const float* __restrict__ b1,
                            const float* __restrict__ w2, const float* __restrict__ b2,
                            const float* __restrict__ w3, const float* __restrict__ b3,
                            float* __restrict__ out, float nf) {
    __shared__ float fp[128], r1[256], r2[256], tc[144], t1[256], t2[256];
    int t = threadIdx.x;
    if (t < 128) {
        float s = nf * pb3[t];
        for (int j = 0; j < 256; ++j) s += gsum[j] * pw3[j * 128 + t];
        fp[t] = s;
    }
    __syncthreads();
    { float s = rb1[t]; for (int f = 0; f < 128; ++f) s += fp[f] * rw1[f * 256 + t]; r1[t] = fmaxf(s, 0.f); }
    __syncthreads();
    { float s = rb2[t]; for (int h = 0; h < 256; ++h) s += r1[h] * rw2[h * 256 + t]; r2[t] = fmaxf(s, 0.f); }
    __syncthreads();
    if (t < 128) {
        float s = rb3[t];
        for (int h = 0; h < 256; ++h) s += r2[h] * rw3[h * 128 + t];
        tc[t] = s;
    } else if (t < 144) {
        tc[t] = xst[t - 128];
    }
    __syncthreads();
    { float s = b1[t]; for (int i = 0; i < 144; ++i) s += tc[i] * w1[i * 256 + t]; t1[t] = fmaxf(s, 0.f); }
    __syncthreads();
    { float s = b2[t]; for (int h = 0; h < 256; ++h) s += t1[h] * w2[h * 256 + t]; t2[t] = fmaxf(s, 0.f); }
    __syncthreads();
    if (t < 5) {
        float s = b3[t];
        for (int h = 0; h < 256; ++h) s += t2[h] * w3[h * 5 + t];
        out[t] = s;
    }
}

extern "C" void kernel_launch(void* const* d_in, const int* in_sizes, int n_in,
                              void* d_out, int out_size, void* d_ws, size_t ws_size,
                              hipStream_t stream) {
    (void)n_in; (void)out_size; (void)ws_size;
    const float* x   = (const float*)d_in[0];
    const float* xst = (const float*)d_in[1];
    const float* pw1 = (const float*)d_in[2];
    const float* pb1 = (const float*)d_in[3];
    const float* pw2 = (const float*)d_in[4];
    const float* pb2 = (const float*)d_in[5];
    const float* pw3 = (const float*)d_in[6];
    const float* pb3 = (const float*)d_in[7];
    const float* rw1 = (const float*)d_in[8];
    const float* rb1 = (const float*)d_in[9];
    const float* rw2 = (const float*)d_in[10];
    const float* rb2 = (const float*)d_in[11];
    const float* rw3 = (const float*)d_in[12];
    const float* rb3 = (const float*)d_in[13];
    const float* w1  = (const float*)d_in[14];
    const float* b1  = (const float*)d_in[15];
    const float* w2  = (const float*)d_in[16];
    const float* b2  = (const float*)d_in[17];
    const float* w3  = (const float*)d_in[18];
    const float* b3  = (const float*)d_in[19];
    float* out = (float*)d_out;

    int n = in_sizes[0] / 64;      // 400000
    int ntiles = n >> 6;           // 6250 (exact)

    char* ws = (char*)d_ws;
    float* gsum = (float*)ws;                    // 256 f32
    u16* w1hi = (u16*)(ws + 1024);               // 16384 bf16
    u16* w1lo = (u16*)(ws + 33792);              // 16384 bf16
    u16* w2hi = (u16*)(ws + 66560);              // 65536 bf16
    u16* w2lo = (u16*)(ws + 197632);             // 65536 bf16

    prep_kernel<<<160, 512, 0, stream>>>(pw1, pw2, w1hi, w1lo, w2hi, w2lo, gsum);
    phi_kernel<<<NBLK, 512, 0, stream>>>(x, pb1, pb2, w1hi, w1lo, w2hi, w2lo, gsum, ntiles);
    tail_kernel<<<1, 256, 0, stream>>>(gsum, xst, pw3, pb3, rw1, rb1, rw2, rb2,
                                       rw3, rb3, w1, b1, w2, b2, w3, b3, out, (float)n);
}

// Round 5
// 127.851 us; speedup vs baseline: 1.8481x; 1.6814x over previous
//
#include <hip/hip_runtime.h>

// DeepSets fused kernel for MI355X (gfx950) — round 3 design (2nd resubmit;
// rounds 3 and 4 both died with UnresponsiveContainer before the job was even
// delivered — no compile, no run, no data).
// All-fp16 single-precision MFMA (v_mfma_f32_16x16x32_f16), weights truly
// resident in VGPRs: waves_per_eu(2,2) raises the VGPR budget to 256 and an
// opaque asm touch prevents the compiler rematerializing the weight loads
// (round-2 failure mode: VGPR capped at 128 -> per-iter L2 re-streams).
// Persistent 256 blocks (1/CU), one barrier per tile, x double-buffered.

typedef unsigned short u16;
typedef _Float16 f16x8 __attribute__((ext_vector_type(8)));
typedef _Float16 f16x4 __attribute__((ext_vector_type(4)));
typedef float f32x4 __attribute__((ext_vector_type(4)));
typedef int i32x4 __attribute__((ext_vector_type(4)));

#define NBLK 256

// ---------------- prep: fp32 weights -> fp16 fragments, zero gsum -----------
// Fragment layout (validated r1/r2): lane l, elem j holds W[k=32*ks+8*(l>>4)+j][16*ctg+(l&15)]
// at frag[((ctg*KS+ks)*64 + l)*8 + j]. Used as MFMA *A* operand: D = W^T X^T = (XW)^T.
__global__ void prep_kernel(const float* __restrict__ pw1, const float* __restrict__ pw2,
                            _Float16* __restrict__ w1f, _Float16* __restrict__ w2f,
                            float* __restrict__ gsum) {
    int idx = blockIdx.x * blockDim.x + threadIdx.x;   // 160*512 = 81920
    if (idx < 256) gsum[idx] = 0.f;
    if (idx < 16384) {  // pw1: 64x256, KS=2
        int j = idx & 7, l = (idx >> 3) & 63, ks = (idx >> 9) & 1, ct = idx >> 10;
        int k = 32 * ks + 8 * (l >> 4) + j;
        int col = 16 * ct + (l & 15);
        w1f[idx] = (_Float16)pw1[k * 256 + col];
    } else {            // pw2: 256x256, KS=8
        int o = idx - 16384;
        int j = o & 7, l = (o >> 3) & 63, ks = (o >> 9) & 7, ct = o >> 12;
        int k = 32 * ks + 8 * (l >> 4) + j;
        int col = 16 * ct + (l & 15);
        w2f[o] = (_Float16)pw2[k * 256 + col];
    }
}

__device__ __forceinline__ void pin_reg(f16x8& v) {
    i32x4 t = __builtin_bit_cast(i32x4, v);
    asm volatile("" : "+v"(t));
    v = __builtin_bit_cast(f16x8, t);
}

// ---------------- fused phi + pool (persistent) ------------------------------
__global__ __attribute__((amdgpu_flat_work_group_size(512, 512), amdgpu_waves_per_eu(2, 2)))
void phi_kernel(
    const float* __restrict__ x,
    const float* __restrict__ pb1, const float* __restrict__ pb2,
    const _Float16* __restrict__ w1g, const _Float16* __restrict__ w2g,
    float* __restrict__ gsum, int ntiles) {
    __shared__ __align__(16) u16 xs[2][64 * 64];    // x tile fp16, swz ^((row&7)<<4)
    __shared__ __align__(16) u16 h1s[2][64 * 256];  // h1 tile fp16, swz ^((row&15)<<4)

    const int tid = threadIdx.x;
    const int l = tid & 63;
    const int w = tid >> 6;
    const int fr = l & 15;
    const int fg = l >> 4;
    const int wb = w * 32;

    // ---- preload weight fragments into registers (loop-invariant, pinned)
    f16x8 w1r[2][2];   // [ct][ks]
#pragma unroll
    for (int ct = 0; ct < 2; ++ct)
#pragma unroll
        for (int ks = 0; ks < 2; ++ks) {
            int ctg = 2 * w + ct;
            w1r[ct][ks] = *(const f16x8*)(w1g + (((ctg << 1) + ks) << 9) + (l << 3));
        }
    f16x8 w2r[2][8];   // [ct][ks]
#pragma unroll
    for (int ct = 0; ct < 2; ++ct)
#pragma unroll
        for (int ks = 0; ks < 8; ++ks) {
            int ctg = 2 * w + ct;
            w2r[ct][ks] = *(const f16x8*)(w2g + (((ctg << 3) + ks) << 9) + (l << 3));
        }
#pragma unroll
    for (int ct = 0; ct < 2; ++ct) {
#pragma unroll
        for (int ks = 0; ks < 2; ++ks) pin_reg(w1r[ct][ks]);
#pragma unroll
        for (int ks = 0; ks < 8; ++ks) pin_reg(w2r[ct][ks]);
    }
    f32x4 b1v[2], b2v[2];
#pragma unroll
    for (int ct = 0; ct < 2; ++ct) {
        int c0 = wb + ct * 16 + fg * 4;
        b1v[ct] = *(const f32x4*)(pb1 + c0);
        b2v[ct] = *(const f32x4*)(pb2 + c0);
    }

    float psum[2][4] = {{0.f, 0.f, 0.f, 0.f}, {0.f, 0.f, 0.f, 0.f}};

    const int t0 = blockIdx.x;
    // ---- prologue: stage tile t0 into xs[0], prefetch t0+NBLK into regs
    {
        const float4* xg = (const float4*)(x + (size_t)t0 * 4096);
#pragma unroll
        for (int i = 0; i < 2; ++i) {
            int f4 = tid + i * 512;
            float4 v = xg[f4];
            int row = f4 >> 4, c4 = f4 & 15;
            f16x4 b;
            b[0] = (_Float16)v.x; b[1] = (_Float16)v.y;
            b[2] = (_Float16)v.z; b[3] = (_Float16)v.w;
            int byte = (row * 128 + c4 * 8) ^ ((row & 7) << 4);
            *(f16x4*)((char*)xs[0] + byte) = b;
        }
    }
    float4 pf0, pf1;
    {
        int tn = (t0 + NBLK < ntiles) ? t0 + NBLK : 0;
        const float4* xg = (const float4*)(x + (size_t)tn * 4096);
        pf0 = xg[tid];
        pf1 = xg[tid + 512];
    }
    __syncthreads();

    int buf = 0, hb = 0;
    for (int t = t0; t < ntiles; t += NBLK) {
        // ---- GEMM1: D1 = (x@pw1)^T from xs[buf]
        {
            f32x4 acc[2][4] = {};
#pragma unroll
            for (int ks = 0; ks < 2; ++ks) {
                f16x8 bd[4];
#pragma unroll
                for (int rt = 0; rt < 4; ++rt) {
                    int row = (rt << 4) + fr;
                    int byte = ((row << 7) + (ks << 6) + (fg << 4)) ^ ((row & 7) << 4);
                    bd[rt] = *(const f16x8*)((char*)xs[buf] + byte);
                }
#pragma unroll
                for (int ct = 0; ct < 2; ++ct)
#pragma unroll
                    for (int rt = 0; rt < 4; ++rt)
                        acc[ct][rt] = __builtin_amdgcn_mfma_f32_16x16x32_f16(w1r[ct][ks], bd[rt], acc[ct][rt], 0, 0, 0);
            }
            // epilogue: bias+relu; lane holds h-cols c0..c0+3 of row rown -> b64 write
#pragma unroll
            for (int ct = 0; ct < 2; ++ct) {
                int c0 = wb + ct * 16 + fg * 4;
#pragma unroll
                for (int rt = 0; rt < 4; ++rt) {
                    int rown = (rt << 4) + fr;
                    f16x4 o;
                    o[0] = (_Float16)fmaxf(acc[ct][rt][0] + b1v[ct][0], 0.f);
                    o[1] = (_Float16)fmaxf(acc[ct][rt][1] + b1v[ct][1], 0.f);
                    o[2] = (_Float16)fmaxf(acc[ct][rt][2] + b1v[ct][2], 0.f);
                    o[3] = (_Float16)fmaxf(acc[ct][rt][3] + b1v[ct][3], 0.f);
                    int byte = ((rown << 9) + (c0 << 1)) ^ ((rown & 15) << 4);
                    *(f16x4*)((char*)h1s[hb] + byte) = o;
                }
            }
        }
        // ---- stage next x tile (regs -> xs[buf^1]); prefetch t+2*NBLK
#pragma unroll
        for (int i = 0; i < 2; ++i) {
            float4 v = i ? pf1 : pf0;
            int f4 = tid + i * 512;
            int row = f4 >> 4, c4 = f4 & 15;
            f16x4 b;
            b[0] = (_Float16)v.x; b[1] = (_Float16)v.y;
            b[2] = (_Float16)v.z; b[3] = (_Float16)v.w;
            int byte = (row * 128 + c4 * 8) ^ ((row & 7) << 4);
            *(f16x4*)((char*)xs[buf ^ 1] + byte) = b;
        }
        {
            int tn = (t + 2 * NBLK < ntiles) ? t + 2 * NBLK : 0;
            const float4* xg = (const float4*)(x + (size_t)tn * 4096);
            pf0 = xg[tid];
            pf1 = xg[tid + 512];
        }
        __syncthreads();   // h1s[hb] + xs[buf^1] now visible

        // ---- GEMM2: D2 = (h1@pw2)^T, pool into psum
        {
            f32x4 acc2[2][4] = {};
#pragma unroll
            for (int ks = 0; ks < 8; ++ks) {
                f16x8 bd[4];
#pragma unroll
                for (int rt = 0; rt < 4; ++rt) {
                    int row = (rt << 4) + fr;
                    int byte = ((row << 9) + (ks << 6) + (fg << 4)) ^ ((row & 15) << 4);
                    bd[rt] = *(const f16x8*)((char*)h1s[hb] + byte);
                }
#pragma unroll
                for (int ct = 0; ct < 2; ++ct)
#pragma unroll
                    for (int rt = 0; rt < 4; ++rt)
                        acc2[ct][rt] = __builtin_amdgcn_mfma_f32_16x16x32_f16(w2r[ct][ks], bd[rt], acc2[ct][rt], 0, 0, 0);
            }
#pragma unroll
            for (int ct = 0; ct < 2; ++ct)
#pragma unroll
                for (int r = 0; r < 4; ++r) {
                    float v = 0.f;
#pragma unroll
                    for (int rt = 0; rt < 4; ++rt)
                        v += fmaxf(acc2[ct][rt][r] + b2v[ct][r], 0.f);
                    psum[ct][r] += v;
                }
        }
        buf ^= 1;
        hb ^= 1;
    }

    // ---- final: reduce psum over the 16 fr-lanes, one atomicAdd per col
#pragma unroll
    for (int ct = 0; ct < 2; ++ct)
#pragma unroll
        for (int r = 0; r < 4; ++r) {
            float v = psum[ct][r];
            v += __shfl_xor(v, 1, 64);
            v += __shfl_xor(v, 2, 64);
            v += __shfl_xor(v, 4, 64);
            v += __shfl_xor(v, 8, 64);
            if (fr == 0) atomicAdd(&gsum[wb + ct * 16 + fg * 4 + r], v);
        }
}

// ---------------- tail: pw3-pool collapse + rho + head (fp32, one block) ----
__global__ void tail_kernel(const float* __restrict__ gsum, const float* __restrict__ xst,
                            const float* __restrict__ pw3, const float* __restrict__ pb3,
                            const float* __restrict__ rw1, const float* __restrict__ rb1,
                            const float* __restrict__ rw2, const float* __restrict__ rb2,
                            const float* __restrict__ rw3, const float* __restrict__ rb3,
                            const float* __restrict__ w1, const float* __restrict__ b1,
                            const float* __restrict__ w2, const float* __restrict__ b2,
                            const float* __restrict__ w3, const float* __restrict__ b3,
                            float* __restrict__ out, float nf) {
    __shared__ float fp[128], r1[256], r2[256], tc[144], t1[256], t2[256];
    int t = threadIdx.x;
    if (t < 128) {
        float s = nf * pb3[t];
        for (int j = 0; j < 256; ++j) s += gsum[j] * pw3[j * 128 + t];
        fp[t] = s;
    }
    __syncthreads();
    { float s = rb1[t]; for (int f = 0; f < 128; ++f) s += fp[f] * rw1[f * 256 + t]; r1[t] = fmaxf(s, 0.f); }
    __syncthreads();
    { float s = rb2[t]; for (int h = 0; h < 256; ++h) s += r1[h] * rw2[h * 256 + t]; r2[t] = fmaxf(s, 0.f); }
    __syncthreads();
    if (t < 128) {
        float s = rb3[t];
        for (int h = 0; h < 256; ++h) s += r2[h] * rw3[h * 128 + t];
        tc[t] = s;
    } else if (t < 144) {
        tc[t] = xst[t - 128];
    }
    __syncthreads();
    { float s = b1[t]; for (int i = 0; i < 144; ++i) s += tc[i] * w1[i * 256 + t]; t1[t] = fmaxf(s, 0.f); }
    __syncthreads();
    { float s = b2[t]; for (int h = 0; h < 256; ++h) s += t1[h] * w2[h * 256 + t]; t2[t] = fmaxf(s, 0.f); }
    __syncthreads();
    if (t < 5) {
        float s = b3[t];
        for (int h = 0; h < 256; ++h) s += t2[h] * w3[h * 5 + t];
        out[t] = s;
    }
}

extern "C" void kernel_launch(void* const* d_in, const int* in_sizes, int n_in,
                              void* d_out, int out_size, void* d_ws, size_t ws_size,
                              hipStream_t stream) {
    (void)n_in; (void)out_size; (void)ws_size;
    const float* x   = (const float*)d_in[0];
    const float* xst = (const float*)d_in[1];
    const float* pw1 = (const float*)d_in[2];
    const float* pb1 = (const float*)d_in[3];
    const float* pw2 = (const float*)d_in[4];
    const float* pb2 = (const float*)d_in[5];
    const float* pw3 = (const float*)d_in[6];
    const float* pb3 = (const float*)d_in[7];
    const float* rw1 = (const float*)d_in[8];
    const float* rb1 = (const float*)d_in[9];
    const float* rw2 = (const float*)d_in[10];
    const float* rb2 = (const float*)d_in[11];
    const float* rw3 = (const float*)d_in[12];
    const float* rb3 = (const float*)d_in[13];
    const float* w1  = (const float*)d_in[14];
    const float* b1  = (const float*)d_in[15];
    const float* w2  = (const float*)d_in[16];
    const float* b2  = (const float*)d_in[17];
    const float* w3  = (const float*)d_in[18];
    const float* b3  = (const float*)d_in[19];
    float* out = (float*)d_out;

    int n = in_sizes[0] / 64;      // 400000
    int ntiles = n >> 6;           // 6250 (exact)

    char* ws = (char*)d_ws;
    float* gsum = (float*)ws;                       // 256 f32 (1KB)
    _Float16* w1f = (_Float16*)(ws + 1024);         // 16384 f16 (32KB)
    _Float16* w2f = (_Float16*)(ws + 1024 + 32768); // 65536 f16 (128KB)

    prep_kernel<<<160, 512, 0, stream>>>(pw1, pw2, w1f, w2f, gsum);
    phi_kernel<<<NBLK, 512, 0, stream>>>(x, pb1, pb2, w1f, w2f, gsum, ntiles);
    tail_kernel<<<1, 256, 0, stream>>>(gsum, xst, pw3, pb3, rw1, rb1, rw2, rb2,
                                       rw3, rb3, w1, b1, w2, b2, w3, b3, out, (float)n);
}